// Round 13
// baseline (4417.129 us; speedup 1.0000x reference)
//
#include <hip/hip_runtime.h>

#define NF 32
#define HDIM 256
#define SLEN 256
#define BATCH 1024

typedef float f32x4 __attribute__((ext_vector_type(4)));
typedef __bf16 bf16x8 __attribute__((ext_vector_type(8)));
typedef unsigned short u16;

#define MFMA __builtin_amdgcn_mfma_f32_16x16x32_bf16
#define BC(x) __builtin_bit_cast(bf16x8, x)

// ---- ws layout ----
#define WHH_O 0       // 64 j * 8 t * 64 l  = 32768 slots
#define WIH_O 32768   // 64 j * 64 l        =  4096
#define WOUT_O 36864  //  2 j * 8 t * 64 l  =  1024
#define WLAT_O 37888  // 32 j * 2 t * 64 l  =  4096
#define PREP1_N 41984
#define WT_BYTE (1u << 20)
#define HST_BYTE (8u << 20)

__device__ __forceinline__ u16 f2bf(float x) {
  __bf16 b = (__bf16)x;
  return __builtin_bit_cast(u16, b);
}
__device__ __forceinline__ unsigned int pk2(float a, float b) {
  return (unsigned int)f2bf(a) | ((unsigned int)f2bf(b) << 16);
}
__device__ __forceinline__ float sigf(float x) {
  return __fdividef(1.0f, 1.0f + __expf(-x));
}
__device__ __forceinline__ float tanhf_(float x) {
  return 1.0f - __fdividef(2.0f, __expf(2.0f * x) + 1.0f);
}
__device__ __forceinline__ void wg_barrier_lds() {
  asm volatile("s_waitcnt lgkmcnt(0)" ::: "memory");
  __builtin_amdgcn_s_barrier();
}

__global__ void prep_weights(const float* __restrict__ Whh, const float* __restrict__ Wih,
                             const float* __restrict__ Wout, const float* __restrict__ Wlat,
                             uint4* __restrict__ ws) {
  int i = blockIdx.x * 256 + threadIdx.x;
  if (i >= PREP1_N) return;
  int l = i & 63;
  int c16 = l & 15, g4 = l >> 4;
  const float* src;
  if (i < WIH_O) {
    int t = (i >> 6) & 7, j = i >> 9;
    src = Whh + (j * 16 + c16) * 256 + t * 32 + 8 * g4;
  } else if (i < WOUT_O) {
    int ii = i - WIH_O;
    int j = ii >> 6;
    src = Wih + (j * 16 + c16) * 32 + 8 * g4;
  } else if (i < WLAT_O) {
    int ii = i - WOUT_O;
    int t = (ii >> 6) & 7, j = ii >> 9;
    src = Wout + (j * 16 + c16) * 256 + t * 32 + 8 * g4;
  } else {
    int ii = i - WLAT_O;
    int t = (ii >> 6) & 1, j = ii >> 7;
    src = Wlat + (j * 16 + c16) * 64 + t * 32 + 8 * g4;
  }
  uint4 P;
  P.x = pk2(src[0], src[1]);
  P.y = pk2(src[2], src[3]);
  P.z = pk2(src[4], src[5]);
  P.w = pk2(src[6], src[7]);
  ws[i] = P;
}

__global__ void prep_wt(const float* __restrict__ Wsig, unsigned short* __restrict__ Wt) {
  __shared__ float tile[32][257];
  int f = blockIdx.x >> 3, hb = blockIdx.x & 7;
  int tid = threadIdx.x;
  const float* src = Wsig + f * (HDIM * SLEN) + hb * 32 * 256;
#pragma unroll
  for (int i = 0; i < 32; ++i) tile[i][tid] = src[i * 256 + tid];
  __syncthreads();
  int s = tid;
  unsigned short tmp[32];
#pragma unroll
  for (int h = 0; h < 32; ++h) tmp[h] = f2bf(tile[h][s]);
  uint4* dst = (uint4*)(Wt + f * 65536 + s * 256 + hb * 32);
  const uint4* tsrc = (const uint4*)tmp;
#pragma unroll
  for (int j = 0; j < 4; ++j) dst[j] = tsrc[j];
}

// Persistent LSTM scan: 64 WGs x 16 batch rows, 16 waves, 256 steps.
// Wave w owns j-tiles {w,16+w,32+w,48+w}. W_hh streamed from L2 via 4 named
// pf slots (static rotation, zero reg copies, 4-kt prefetch distance; next
// step's kt0-3 issue before the barriers). x-GEMM + hst copy overlapped
// into phase A. lgkm-only barriers. Swizzle offsets precomputed.
__global__ __launch_bounds__(1024, 4) void lstm_scan(
    const float* __restrict__ z, const float* __restrict__ b_lat,
    const float* __restrict__ b_ih, const float* __restrict__ b_hh,
    const float* __restrict__ b_out,
    const uint4* __restrict__ ws, unsigned short* __restrict__ hst,
    float* __restrict__ out) {
  __shared__ __align__(16) uint4 wihl[4096];              // 64KB
  __shared__ __align__(16) uint4 woutb[1024];             // 16KB
  __shared__ __align__(16) u16 hbuf[2][16][256];          // 16KB (swizzled)
  __shared__ __align__(16) u16 thbuf[16][256];            // 8KB  (swizzled; z-stage)
  __shared__ __align__(16) u16 xbuf[16][32];              // 1KB
  __shared__ __align__(16) float mubuf[16][16][32];       // 32KB

  const int tid = threadIdx.x, w = tid >> 6, l = tid & 63;
  const int c16 = l & 15, g4 = l >> 4, r0 = g4 * 4;
  const int wg = blockIdx.x;
  const int swz = (c16 & 7) << 3;

  for (int i = tid; i < 4096; i += 1024) wihl[i] = ws[WIH_O + i];
  if (tid < 1024) woutb[tid] = ws[WOUT_O + tid];

  const uint4* bs0 = ws + WHH_O + ((0 * 16 + w) * 8 + 4) * 64 + l;
  const uint4* bs1 = ws + WHH_O + ((1 * 16 + w) * 8 + 4) * 64 + l;
  const uint4* bs2 = ws + WHH_O + ((2 * 16 + w) * 8 + 4) * 64 + l;
  const uint4* bs3 = ws + WHH_O + ((3 * 16 + w) * 8 + 4) * 64 + l;

  float biasv[4];
#pragma unroll
  for (int gi = 0; gi < 4; ++gi) {
    int n = (gi * 16 + w) * 16 + c16;
    biasv[gi] = b_ih[n] + b_hh[n];
  }
  const int jn = w - 14;
  const float bo = (w >= 14) ? b_out[jn * 16 + c16] : 0.f;
  const int hc = w * 16 + c16;

  // precomputed LDS element offsets (registers; zero in-loop addr VALU)
  const int eo0 = (0 * 32 + 8 * g4) ^ swz, eo1 = (1 * 32 + 8 * g4) ^ swz;
  const int eo2 = (2 * 32 + 8 * g4) ^ swz, eo3 = (3 * 32 + 8 * g4) ^ swz;
  const int eo4 = (4 * 32 + 8 * g4) ^ swz, eo5 = (5 * 32 + 8 * g4) ^ swz;
  const int eo6 = (6 * 32 + 8 * g4) ^ swz, eo7 = (7 * 32 + 8 * g4) ^ swz;
  const int so0 = hc ^ (((r0 + 0) & 7) << 3), so1 = hc ^ (((r0 + 1) & 7) << 3);
  const int so2 = hc ^ (((r0 + 2) & 7) << 3), so3 = hc ^ (((r0 + 3) & 7) << 3);

  // ---- init: z -> thbuf staging, x0 = 0 ----
  thbuf[tid >> 6][tid & 63] = f2bf(z[(wg * 16 + (tid >> 6)) * 64 + (tid & 63)]);
  if (tid < 512) xbuf[tid >> 5][tid & 31] = 0;
  __syncthreads();

  float cst[4];
  {
    bf16x8 za0 = *reinterpret_cast<const bf16x8*>(&thbuf[c16][8 * g4]);
    bf16x8 za1 = *reinterpret_cast<const bf16x8*>(&thbuf[c16][32 + 8 * g4]);
    float blh = b_lat[w * 16 + c16];
    float blc = b_lat[256 + w * 16 + c16];
    f32x4 ah = {blh, blh, blh, blh}, ac = {blc, blc, blc, blc};
    ah = MFMA(za0, *reinterpret_cast<const bf16x8*>(ws + WLAT_O + (w * 2 + 0) * 64 + l), ah, 0, 0, 0);
    ah = MFMA(za1, *reinterpret_cast<const bf16x8*>(ws + WLAT_O + (w * 2 + 1) * 64 + l), ah, 0, 0, 0);
    ac = MFMA(za0, *reinterpret_cast<const bf16x8*>(ws + WLAT_O + ((16 + w) * 2 + 0) * 64 + l), ac, 0, 0, 0);
    ac = MFMA(za1, *reinterpret_cast<const bf16x8*>(ws + WLAT_O + ((16 + w) * 2 + 1) * 64 + l), ac, 0, 0, 0);
    cst[0] = ac[0]; cst[1] = ac[1]; cst[2] = ac[2]; cst[3] = ac[3];
    hbuf[0][r0 + 0][so0] = f2bf(ah[0]);
    hbuf[0][r0 + 1][so1] = f2bf(ah[1]);
    hbuf[0][r0 + 2][so2] = f2bf(ah[2]);
    hbuf[0][r0 + 3][so3] = f2bf(ah[3]);
  }
  __syncthreads();

  // prologue: preload kt0..kt3 into pf0..pf3
  uint4 pf0[4], pf1[4], pf2[4], pf3[4];
#define LOADPF(PF, OFF) \
  PF[0] = bs0[(OFF) * 64]; PF[1] = bs1[(OFF) * 64]; \
  PF[2] = bs2[(OFF) * 64]; PF[3] = bs3[(OFF) * 64];
  LOADPF(pf0, -4) LOADPF(pf1, -3) LOADPF(pf2, -2) LOADPF(pf3, -1)

// one kt sub-step: ds_read A-frag, 4 MFMAs from PF, refill PF for kt+4
#define GKT(PB, EO, PF, LOFF) { \
    bf16x8 afr = *reinterpret_cast<const bf16x8*>(&hbuf[PB][c16][EO]); \
    acc[0] = MFMA(afr, BC(PF[0]), acc[0], 0, 0, 0); \
    acc[1] = MFMA(afr, BC(PF[1]), acc[1], 0, 0, 0); \
    acc[2] = MFMA(afr, BC(PF[2]), acc[2], 0, 0, 0); \
    acc[3] = MFMA(afr, BC(PF[3]), acc[3], 0, 0, 0); \
    LOADPF(PF, LOFF) }

#define STEP(PB, S_) { \
    const int s_ = (S_); \
    f32x4 acc[4]; \
    acc[0] = (f32x4){biasv[0], biasv[0], biasv[0], biasv[0]}; \
    acc[1] = (f32x4){biasv[1], biasv[1], biasv[1], biasv[1]}; \
    acc[2] = (f32x4){biasv[2], biasv[2], biasv[2], biasv[2]}; \
    acc[3] = (f32x4){biasv[3], biasv[3], biasv[3], biasv[3]}; \
    f32x4 xacc = {bo, bo, bo, bo}; \
    /* phase A: x-waves do x_s first so xbuf lands before B1 */ \
    if (w >= 14 && s_ > 0) { \
      xacc = MFMA(*reinterpret_cast<const bf16x8*>(&thbuf[c16][eo0]), BC(woutb[(jn * 8 + 0) * 64 + l]), xacc, 0, 0, 0); \
      xacc = MFMA(*reinterpret_cast<const bf16x8*>(&thbuf[c16][eo1]), BC(woutb[(jn * 8 + 1) * 64 + l]), xacc, 0, 0, 0); \
      xacc = MFMA(*reinterpret_cast<const bf16x8*>(&thbuf[c16][eo2]), BC(woutb[(jn * 8 + 2) * 64 + l]), xacc, 0, 0, 0); \
      xacc = MFMA(*reinterpret_cast<const bf16x8*>(&thbuf[c16][eo3]), BC(woutb[(jn * 8 + 3) * 64 + l]), xacc, 0, 0, 0); \
      xacc = MFMA(*reinterpret_cast<const bf16x8*>(&thbuf[c16][eo4]), BC(woutb[(jn * 8 + 4) * 64 + l]), xacc, 0, 0, 0); \
      xacc = MFMA(*reinterpret_cast<const bf16x8*>(&thbuf[c16][eo5]), BC(woutb[(jn * 8 + 5) * 64 + l]), xacc, 0, 0, 0); \
      xacc = MFMA(*reinterpret_cast<const bf16x8*>(&thbuf[c16][eo6]), BC(woutb[(jn * 8 + 6) * 64 + l]), xacc, 0, 0, 0); \
      xacc = MFMA(*reinterpret_cast<const bf16x8*>(&thbuf[c16][eo7]), BC(woutb[(jn * 8 + 7) * 64 + l]), xacc, 0, 0, 0); \
      const int f = jn * 16 + c16; \
      xbuf[r0 + 0][f] = f2bf(xacc[0]); \
      xbuf[r0 + 1][f] = f2bf(xacc[1]); \
      xbuf[r0 + 2][f] = f2bf(xacc[2]); \
      xbuf[r0 + 3][f] = f2bf(xacc[3]); \
    } \
    __builtin_amdgcn_s_setprio(1); \
    GKT(PB, eo0, pf0, 0) GKT(PB, eo1, pf1, 1) GKT(PB, eo2, pf2, 2) GKT(PB, eo3, pf3, 3) \
    GKT(PB, eo4, pf0, -4) GKT(PB, eo5, pf1, -3) GKT(PB, eo6, pf2, -2) GKT(PB, eo7, pf3, -1) \
    __builtin_amdgcn_s_setprio(0); \
    if (w >= 6 && w < 14 && s_ > 0) { \
      int task = (w - 6) * 64 + l; \
      int r = task >> 5, h0 = (task & 31) * 8; \
      uint4 d = *reinterpret_cast<const uint4*>(&hbuf[PB][r][h0 ^ ((r & 7) << 3)]); \
      *reinterpret_cast<uint4*>(hst + ((wg * 16 + r) << 16) + ((s_ - 1) << 8) + h0) = d; \
    } \
    wg_barrier_lds(); /* B1: xbuf ready */ \
    { \
      bf16x8 xfr = *reinterpret_cast<const bf16x8*>(&xbuf[c16][8 * g4]); \
      acc[0] = MFMA(xfr, BC(wihl[(0 * 16 + w) * 64 + l]), acc[0], 0, 0, 0); \
      acc[1] = MFMA(xfr, BC(wihl[(1 * 16 + w) * 64 + l]), acc[1], 0, 0, 0); \
      acc[2] = MFMA(xfr, BC(wihl[(2 * 16 + w) * 64 + l]), acc[2], 0, 0, 0); \
      acc[3] = MFMA(xfr, BC(wihl[(3 * 16 + w) * 64 + l]), acc[3], 0, 0, 0); \
    } \
    { \
      float iv, fv, gv, ov, cc, hh, th; \
      iv = acc[0][0]; fv = acc[1][0]; gv = acc[2][0]; ov = acc[3][0]; \
      cc = sigf(fv) * cst[0] + sigf(iv) * tanhf_(gv); cst[0] = cc; \
      hh = sigf(ov) * tanhf_(cc); th = tanhf_(hh); \
      hbuf[PB ^ 1][r0 + 0][so0] = f2bf(hh); thbuf[r0 + 0][so0] = f2bf(th); \
      iv = acc[0][1]; fv = acc[1][1]; gv = acc[2][1]; ov = acc[3][1]; \
      cc = sigf(fv) * cst[1] + sigf(iv) * tanhf_(gv); cst[1] = cc; \
      hh = sigf(ov) * tanhf_(cc); th = tanhf_(hh); \
      hbuf[PB ^ 1][r0 + 1][so1] = f2bf(hh); thbuf[r0 + 1][so1] = f2bf(th); \
      iv = acc[0][2]; fv = acc[1][2]; gv = acc[2][2]; ov = acc[3][2]; \
      cc = sigf(fv) * cst[2] + sigf(iv) * tanhf_(gv); cst[2] = cc; \
      hh = sigf(ov) * tanhf_(cc); th = tanhf_(hh); \
      hbuf[PB ^ 1][r0 + 2][so2] = f2bf(hh); thbuf[r0 + 2][so2] = f2bf(th); \
      iv = acc[0][3]; fv = acc[1][3]; gv = acc[2][3]; ov = acc[3][3]; \
      cc = sigf(fv) * cst[3] + sigf(iv) * tanhf_(gv); cst[3] = cc; \
      hh = sigf(ov) * tanhf_(cc); th = tanhf_(hh); \
      hbuf[PB ^ 1][r0 + 3][so3] = f2bf(hh); thbuf[r0 + 3][so3] = f2bf(th); \
    } \
    if (w >= 14 && s_ > 0) { \
      const int f = jn * 16 + c16, mi = (s_ - 1) & 15; \
      mubuf[mi][r0 + 0][f] = xacc[0]; \
      mubuf[mi][r0 + 1][f] = xacc[1]; \
      mubuf[mi][r0 + 2][f] = xacc[2]; \
      mubuf[mi][r0 + 3][f] = xacc[3]; \
    } \
    wg_barrier_lds(); /* B2: h_{s+1}/th_{s+1}/mu ready */ \
    if ((s_ & 15) == 0 && s_ > 0 && tid < 512) { \
      int b = tid >> 5, f = tid & 31; \
      float* dst = out + ((wg * 16 + b) << 13) + (f << 8) + (s_ - 16); \
      _Pragma("unroll") for (int j4 = 0; j4 < 4; ++j4) { \
        f32x4 vv; \
        _Pragma("unroll") for (int jj = 0; jj < 4; ++jj) vv[jj] = mubuf[j4 * 4 + jj][b][f]; \
        *reinterpret_cast<f32x4*>(dst + j4 * 4) = vv; \
      } \
    } \
  }

  for (int sp = 0; sp < 128; ++sp) {
    STEP(0, 2 * sp)
    STEP(1, 2 * sp + 1)
  }

  // ---- tail: x_256 -> mu col 255; flush cols 240-255; hst slot 255 ----
  if (w >= 14) {
    f32x4 xacc = {bo, bo, bo, bo};
    xacc = MFMA(*reinterpret_cast<const bf16x8*>(&thbuf[c16][eo0]), BC(woutb[(jn * 8 + 0) * 64 + l]), xacc, 0, 0, 0);
    xacc = MFMA(*reinterpret_cast<const bf16x8*>(&thbuf[c16][eo1]), BC(woutb[(jn * 8 + 1) * 64 + l]), xacc, 0, 0, 0);
    xacc = MFMA(*reinterpret_cast<const bf16x8*>(&thbuf[c16][eo2]), BC(woutb[(jn * 8 + 2) * 64 + l]), xacc, 0, 0, 0);
    xacc = MFMA(*reinterpret_cast<const bf16x8*>(&thbuf[c16][eo3]), BC(woutb[(jn * 8 + 3) * 64 + l]), xacc, 0, 0, 0);
    xacc = MFMA(*reinterpret_cast<const bf16x8*>(&thbuf[c16][eo4]), BC(woutb[(jn * 8 + 4) * 64 + l]), xacc, 0, 0, 0);
    xacc = MFMA(*reinterpret_cast<const bf16x8*>(&thbuf[c16][eo5]), BC(woutb[(jn * 8 + 5) * 64 + l]), xacc, 0, 0, 0);
    xacc = MFMA(*reinterpret_cast<const bf16x8*>(&thbuf[c16][eo6]), BC(woutb[(jn * 8 + 6) * 64 + l]), xacc, 0, 0, 0);
    xacc = MFMA(*reinterpret_cast<const bf16x8*>(&thbuf[c16][eo7]), BC(woutb[(jn * 8 + 7) * 64 + l]), xacc, 0, 0, 0);
    const int f = jn * 16 + c16;
    mubuf[15][r0 + 0][f] = xacc[0];
    mubuf[15][r0 + 1][f] = xacc[1];
    mubuf[15][r0 + 2][f] = xacc[2];
    mubuf[15][r0 + 3][f] = xacc[3];
  }
  __syncthreads();
  if (tid < 512) {
    int b = tid >> 5, f = tid & 31;
    float* dst = out + ((wg * 16 + b) << 13) + (f << 8) + 240;
#pragma unroll
    for (int j4 = 0; j4 < 4; ++j4) {
      f32x4 vv;
#pragma unroll
      for (int jj = 0; jj < 4; ++jj) vv[jj] = mubuf[j4 * 4 + jj][b][f];
      *reinterpret_cast<f32x4*>(dst + j4 * 4) = vv;
    }
  }
  if (w < 8) {
    int r = tid >> 5;
    int h0 = (tid & 31) * 8;
    uint4 d = *reinterpret_cast<const uint4*>(&hbuf[0][r][h0 ^ ((r & 7) << 3)]);
    *reinterpret_cast<uint4*>(hst + ((wg * 16 + r) << 16) + (255 << 8) + h0) = d;
  }
}

// sigma = softplus(hs_flat @ W_sig^T + b_sig)
__global__ __launch_bounds__(512) void sigma_gemm(
    const unsigned short* __restrict__ hst, const unsigned short* __restrict__ Wt,
    const float* __restrict__ b_sig, float* __restrict__ out) {
  __shared__ float sred[8][16][32];
  const int tid = threadIdx.x;
  const int w = tid >> 6;
  const int l = tid & 63;
  const int c16 = l & 15;
  const int g4 = l >> 4;
  const int wg = blockIdx.x;

  const unsigned short* ap =
      hst + (((wg << 2) + (c16 & 3)) << 16) + ((w * 32) << 8) + (g4 << 3);
  const unsigned short* bp0 = Wt + (c16 << 16) + ((w * 32) << 8) + (g4 << 3);
  const unsigned short* bp1 = Wt + ((16 + c16) << 16) + ((w * 32) << 8) + (g4 << 3);

  f32x4 a0 = {0.f, 0.f, 0.f, 0.f}, a1 = {0.f, 0.f, 0.f, 0.f};
#pragma unroll 8
  for (int kk = 0; kk < 256; ++kk) {
    int off = ((kk >> 3) << 8) + ((kk & 7) << 5);
    bf16x8 av = *reinterpret_cast<const bf16x8*>(ap + off);
    a0 = MFMA(av, *reinterpret_cast<const bf16x8*>(bp0 + off), a0, 0, 0, 0);
    a1 = MFMA(av, *reinterpret_cast<const bf16x8*>(bp1 + off), a1, 0, 0, 0);
  }
#pragma unroll
  for (int v = 0; v < 4; ++v) {
    sred[w][g4 * 4 + v][c16] = a0[v];
    sred[w][g4 * 4 + v][16 + c16] = a1[v];
  }
  __syncthreads();
  int b = tid >> 5, f = tid & 31;
  if (b < 4) {
    float acc = b_sig[f];
#pragma unroll
    for (int ww = 0; ww < 8; ++ww) acc += sred[ww][b][f];
    float sp = fmaxf(acc, 0.0f) + log1pf(__expf(-fabsf(acc)));
    out[BATCH * NF * SLEN + ((wg << 2) + b) * NF + f] = sp;
  }
}

extern "C" void kernel_launch(void* const* d_in, const int* in_sizes, int n_in,
                              void* d_out, int out_size, void* d_ws, size_t ws_size,
                              hipStream_t stream) {
  (void)in_sizes; (void)n_in; (void)out_size; (void)ws_size;
  const float* z     = (const float*)d_in[0];
  const float* W_lat = (const float*)d_in[1];
  const float* b_lat = (const float*)d_in[2];
  const float* W_ih  = (const float*)d_in[3];
  const float* b_ih  = (const float*)d_in[4];
  const float* W_hh  = (const float*)d_in[5];
  const float* b_hh  = (const float*)d_in[6];
  const float* W_out = (const float*)d_in[7];
  const float* b_out = (const float*)d_in[8];
  const float* W_sig = (const float*)d_in[9];
  const float* b_sig = (const float*)d_in[10];
  char* wsb = (char*)d_ws;
  uint4* ws = (uint4*)wsb;
  unsigned short* Wt  = (unsigned short*)(wsb + WT_BYTE);
  unsigned short* hst = (unsigned short*)(wsb + HST_BYTE);
  float* out = (float*)d_out;

  prep_weights<<<(PREP1_N + 255) / 256, 256, 0, stream>>>(W_hh, W_ih, W_out, W_lat, ws);
  prep_wt<<<256, 256, 0, stream>>>(W_sig, Wt);
  lstm_scan<<<64, 1024, 0, stream>>>(z, b_lat, b_ih, b_hh, b_out, ws, hst, out);
  sigma_gemm<<<256, 512, 0, stream>>>(hst, Wt, b_sig, out);
}

// Round 14
// 3829.209 us; speedup vs baseline: 1.1535x; 1.1535x over previous
//
#include <hip/hip_runtime.h>

#define NF 32
#define HDIM 256
#define SLEN 256
#define BATCH 1024

typedef float f32x4 __attribute__((ext_vector_type(4)));
typedef __bf16 bf16x8 __attribute__((ext_vector_type(8)));
typedef unsigned short u16;

#define MFMA __builtin_amdgcn_mfma_f32_16x16x32_bf16
#define BC(x) __builtin_bit_cast(bf16x8, x)

// ---- ws layout ----
#define WHH_O 0       // 64 j * 8 t * 64 l  = 32768 slots
#define WIH_O 32768   // 64 j * 64 l        =  4096
#define WOUT_O 36864  //  2 j * 8 t * 64 l  =  1024
#define WLAT_O 37888  // 32 j * 2 t * 64 l  =  4096
#define PREP1_N 41984
#define WT_BYTE (1u << 20)
#define HST_BYTE (8u << 20)

__device__ __forceinline__ u16 f2bf(float x) {
  __bf16 b = (__bf16)x;
  return __builtin_bit_cast(u16, b);
}
__device__ __forceinline__ unsigned int pk2(float a, float b) {
  return (unsigned int)f2bf(a) | ((unsigned int)f2bf(b) << 16);
}
__device__ __forceinline__ float sigf(float x) {
  return __fdividef(1.0f, 1.0f + __expf(-x));
}
__device__ __forceinline__ float tanhf_(float x) {
  return 1.0f - __fdividef(2.0f, __expf(2.0f * x) + 1.0f);
}
__device__ __forceinline__ void wg_barrier_lds() {
  asm volatile("s_waitcnt lgkmcnt(0)" ::: "memory");
  __builtin_amdgcn_s_barrier();
}

__global__ void prep_weights(const float* __restrict__ Whh, const float* __restrict__ Wih,
                             const float* __restrict__ Wout, const float* __restrict__ Wlat,
                             uint4* __restrict__ ws) {
  int i = blockIdx.x * 256 + threadIdx.x;
  if (i >= PREP1_N) return;
  int l = i & 63;
  int c16 = l & 15, g4 = l >> 4;
  const float* src;
  if (i < WIH_O) {
    int t = (i >> 6) & 7, j = i >> 9;
    src = Whh + (j * 16 + c16) * 256 + t * 32 + 8 * g4;
  } else if (i < WOUT_O) {
    int ii = i - WIH_O;
    int j = ii >> 6;
    src = Wih + (j * 16 + c16) * 32 + 8 * g4;
  } else if (i < WLAT_O) {
    int ii = i - WOUT_O;
    int t = (ii >> 6) & 7, j = ii >> 9;
    src = Wout + (j * 16 + c16) * 256 + t * 32 + 8 * g4;
  } else {
    int ii = i - WLAT_O;
    int t = (ii >> 6) & 1, j = ii >> 7;
    src = Wlat + (j * 16 + c16) * 64 + t * 32 + 8 * g4;
  }
  uint4 P;
  P.x = pk2(src[0], src[1]);
  P.y = pk2(src[2], src[3]);
  P.z = pk2(src[4], src[5]);
  P.w = pk2(src[6], src[7]);
  ws[i] = P;
}

__global__ void prep_wt(const float* __restrict__ Wsig, unsigned short* __restrict__ Wt) {
  __shared__ float tile[32][257];
  int f = blockIdx.x >> 3, hb = blockIdx.x & 7;
  int tid = threadIdx.x;
  const float* src = Wsig + f * (HDIM * SLEN) + hb * 32 * 256;
#pragma unroll
  for (int i = 0; i < 32; ++i) tile[i][tid] = src[i * 256 + tid];
  __syncthreads();
  int s = tid;
  unsigned short tmp[32];
#pragma unroll
  for (int h = 0; h < 32; ++h) tmp[h] = f2bf(tile[h][s]);
  uint4* dst = (uint4*)(Wt + f * 65536 + s * 256 + hb * 32);
  const uint4* tsrc = (const uint4*)tmp;
#pragma unroll
  for (int j = 0; j < 4; ++j) dst[j] = tsrc[j];
}

// Persistent LSTM scan: 64 WGs x 16 batch rows, 16 waves, 256 steps.
// Wave w owns j-tiles {w,16+w,32+w,48+w}. W_hh streamed via TWO named pf
// banks (8 uint4 = 32 regs live, zero copies, 2-kt distance; kt6/kt7 issue
// next step's kt0/kt1 so loads ride across the lgkm-only barriers).
// x-GEMM (waves 14-15) + hst copy (waves 6-13) overlap the gate MFMAs.
__global__ __launch_bounds__(1024, 4) void lstm_scan(
    const float* __restrict__ z, const float* __restrict__ b_lat,
    const float* __restrict__ b_ih, const float* __restrict__ b_hh,
    const float* __restrict__ b_out,
    const uint4* __restrict__ ws, unsigned short* __restrict__ hst,
    float* __restrict__ out) {
  __shared__ __align__(16) uint4 wihl[4096];              // 64KB
  __shared__ __align__(16) uint4 woutb[1024];             // 16KB
  __shared__ __align__(16) u16 hbuf[2][16][256];          // 16KB (swizzled)
  __shared__ __align__(16) u16 thbuf[16][256];            // 8KB  (swizzled; z-stage)
  __shared__ __align__(16) u16 xbuf[16][32];              // 1KB
  __shared__ __align__(16) float mubuf[16][16][32];       // 32KB

  const int tid = threadIdx.x, w = tid >> 6, l = tid & 63;
  const int c16 = l & 15, g4 = l >> 4, r0 = g4 * 4;
  const int wg = blockIdx.x;
  const int swz = (c16 & 7) << 3;

  for (int i = tid; i < 4096; i += 1024) wihl[i] = ws[WIH_O + i];
  if (tid < 1024) woutb[tid] = ws[WOUT_O + tid];

  const uint4* bs0 = ws + WHH_O + ((0 * 16 + w) * 8 + 4) * 64 + l;
  const uint4* bs1 = ws + WHH_O + ((1 * 16 + w) * 8 + 4) * 64 + l;
  const uint4* bs2 = ws + WHH_O + ((2 * 16 + w) * 8 + 4) * 64 + l;
  const uint4* bs3 = ws + WHH_O + ((3 * 16 + w) * 8 + 4) * 64 + l;

  float biasv[4];
#pragma unroll
  for (int gi = 0; gi < 4; ++gi) {
    int n = (gi * 16 + w) * 16 + c16;
    biasv[gi] = b_ih[n] + b_hh[n];
  }
  const int jn = w - 14;
  const float bo = (w >= 14) ? b_out[jn * 16 + c16] : 0.f;
  const int hc = w * 16 + c16;

  // precomputed LDS element offsets
  const int eo0 = (0 * 32 + 8 * g4) ^ swz, eo1 = (1 * 32 + 8 * g4) ^ swz;
  const int eo2 = (2 * 32 + 8 * g4) ^ swz, eo3 = (3 * 32 + 8 * g4) ^ swz;
  const int eo4 = (4 * 32 + 8 * g4) ^ swz, eo5 = (5 * 32 + 8 * g4) ^ swz;
  const int eo6 = (6 * 32 + 8 * g4) ^ swz, eo7 = (7 * 32 + 8 * g4) ^ swz;
  const int so0 = hc ^ (((r0 + 0) & 7) << 3), so1 = hc ^ (((r0 + 1) & 7) << 3);
  const int so2 = hc ^ (((r0 + 2) & 7) << 3), so3 = hc ^ (((r0 + 3) & 7) << 3);

  // ---- init: z -> thbuf staging, x0 = 0 ----
  thbuf[tid >> 6][tid & 63] = f2bf(z[(wg * 16 + (tid >> 6)) * 64 + (tid & 63)]);
  if (tid < 512) xbuf[tid >> 5][tid & 31] = 0;
  __syncthreads();

  float cst[4];
  {
    bf16x8 za0 = *reinterpret_cast<const bf16x8*>(&thbuf[c16][8 * g4]);
    bf16x8 za1 = *reinterpret_cast<const bf16x8*>(&thbuf[c16][32 + 8 * g4]);
    float blh = b_lat[w * 16 + c16];
    float blc = b_lat[256 + w * 16 + c16];
    f32x4 ah = {blh, blh, blh, blh}, ac = {blc, blc, blc, blc};
    ah = MFMA(za0, *reinterpret_cast<const bf16x8*>(ws + WLAT_O + (w * 2 + 0) * 64 + l), ah, 0, 0, 0);
    ah = MFMA(za1, *reinterpret_cast<const bf16x8*>(ws + WLAT_O + (w * 2 + 1) * 64 + l), ah, 0, 0, 0);
    ac = MFMA(za0, *reinterpret_cast<const bf16x8*>(ws + WLAT_O + ((16 + w) * 2 + 0) * 64 + l), ac, 0, 0, 0);
    ac = MFMA(za1, *reinterpret_cast<const bf16x8*>(ws + WLAT_O + ((16 + w) * 2 + 1) * 64 + l), ac, 0, 0, 0);
    cst[0] = ac[0]; cst[1] = ac[1]; cst[2] = ac[2]; cst[3] = ac[3];
    hbuf[0][r0 + 0][so0] = f2bf(ah[0]);
    hbuf[0][r0 + 1][so1] = f2bf(ah[1]);
    hbuf[0][r0 + 2][so2] = f2bf(ah[2]);
    hbuf[0][r0 + 3][so3] = f2bf(ah[3]);
  }
  __syncthreads();

  // prologue: preload kt0 -> pfA, kt1 -> pfB
  uint4 pfA[4], pfB[4];
#define LOADPF(PF, OFF) \
  PF[0] = bs0[(OFF) * 64]; PF[1] = bs1[(OFF) * 64]; \
  PF[2] = bs2[(OFF) * 64]; PF[3] = bs3[(OFF) * 64];
  LOADPF(pfA, -4) LOADPF(pfB, -3)

// one kt sub-step: ds_read A-frag, 4 MFMAs from PF, refill PF for kt+2
#define GKT(PB, EO, PF, LOFF) { \
    bf16x8 afr = *reinterpret_cast<const bf16x8*>(&hbuf[PB][c16][EO]); \
    acc[0] = MFMA(afr, BC(PF[0]), acc[0], 0, 0, 0); \
    acc[1] = MFMA(afr, BC(PF[1]), acc[1], 0, 0, 0); \
    acc[2] = MFMA(afr, BC(PF[2]), acc[2], 0, 0, 0); \
    acc[3] = MFMA(afr, BC(PF[3]), acc[3], 0, 0, 0); \
    LOADPF(PF, LOFF) }

#define STEP(PB, S_) { \
    const int s_ = (S_); \
    f32x4 acc[4]; \
    acc[0] = (f32x4){biasv[0], biasv[0], biasv[0], biasv[0]}; \
    acc[1] = (f32x4){biasv[1], biasv[1], biasv[1], biasv[1]}; \
    acc[2] = (f32x4){biasv[2], biasv[2], biasv[2], biasv[2]}; \
    acc[3] = (f32x4){biasv[3], biasv[3], biasv[3], biasv[3]}; \
    f32x4 xacc = {bo, bo, bo, bo}; \
    /* phase A: x-waves do x_s first so xbuf lands before B1 */ \
    if (w >= 14 && s_ > 0) { \
      xacc = MFMA(*reinterpret_cast<const bf16x8*>(&thbuf[c16][eo0]), BC(woutb[(jn * 8 + 0) * 64 + l]), xacc, 0, 0, 0); \
      xacc = MFMA(*reinterpret_cast<const bf16x8*>(&thbuf[c16][eo1]), BC(woutb[(jn * 8 + 1) * 64 + l]), xacc, 0, 0, 0); \
      xacc = MFMA(*reinterpret_cast<const bf16x8*>(&thbuf[c16][eo2]), BC(woutb[(jn * 8 + 2) * 64 + l]), xacc, 0, 0, 0); \
      xacc = MFMA(*reinterpret_cast<const bf16x8*>(&thbuf[c16][eo3]), BC(woutb[(jn * 8 + 3) * 64 + l]), xacc, 0, 0, 0); \
      xacc = MFMA(*reinterpret_cast<const bf16x8*>(&thbuf[c16][eo4]), BC(woutb[(jn * 8 + 4) * 64 + l]), xacc, 0, 0, 0); \
      xacc = MFMA(*reinterpret_cast<const bf16x8*>(&thbuf[c16][eo5]), BC(woutb[(jn * 8 + 5) * 64 + l]), xacc, 0, 0, 0); \
      xacc = MFMA(*reinterpret_cast<const bf16x8*>(&thbuf[c16][eo6]), BC(woutb[(jn * 8 + 6) * 64 + l]), xacc, 0, 0, 0); \
      xacc = MFMA(*reinterpret_cast<const bf16x8*>(&thbuf[c16][eo7]), BC(woutb[(jn * 8 + 7) * 64 + l]), xacc, 0, 0, 0); \
      const int f = jn * 16 + c16; \
      xbuf[r0 + 0][f] = f2bf(xacc[0]); \
      xbuf[r0 + 1][f] = f2bf(xacc[1]); \
      xbuf[r0 + 2][f] = f2bf(xacc[2]); \
      xbuf[r0 + 3][f] = f2bf(xacc[3]); \
    } \
    __builtin_amdgcn_s_setprio(1); \
    GKT(PB, eo0, pfA, -2) GKT(PB, eo1, pfB, -1) /* kt0,kt1; refill kt2,kt3 */ \
    GKT(PB, eo2, pfA, 0)  GKT(PB, eo3, pfB, 1)  /* kt2,kt3; refill kt4,kt5 */ \
    GKT(PB, eo4, pfA, 2)  GKT(PB, eo5, pfB, 3)  /* kt4,kt5; refill kt6,kt7 */ \
    GKT(PB, eo6, pfA, -4) GKT(PB, eo7, pfB, -3) /* kt6,kt7; refill NEXT kt0,kt1 */ \
    __builtin_amdgcn_s_setprio(0); \
    if (w >= 6 && w < 14 && s_ > 0) { \
      int task = (w - 6) * 64 + l; \
      int r = task >> 5, h0 = (task & 31) * 8; \
      uint4 d = *reinterpret_cast<const uint4*>(&hbuf[PB][r][h0 ^ ((r & 7) << 3)]); \
      *reinterpret_cast<uint4*>(hst + ((wg * 16 + r) << 16) + ((s_ - 1) << 8) + h0) = d; \
    } \
    wg_barrier_lds(); /* B1: xbuf ready */ \
    { \
      bf16x8 xfr = *reinterpret_cast<const bf16x8*>(&xbuf[c16][8 * g4]); \
      acc[0] = MFMA(xfr, BC(wihl[(0 * 16 + w) * 64 + l]), acc[0], 0, 0, 0); \
      acc[1] = MFMA(xfr, BC(wihl[(1 * 16 + w) * 64 + l]), acc[1], 0, 0, 0); \
      acc[2] = MFMA(xfr, BC(wihl[(2 * 16 + w) * 64 + l]), acc[2], 0, 0, 0); \
      acc[3] = MFMA(xfr, BC(wihl[(3 * 16 + w) * 64 + l]), acc[3], 0, 0, 0); \
    } \
    { \
      float iv, fv, gv, ov, cc, hh, th; \
      iv = acc[0][0]; fv = acc[1][0]; gv = acc[2][0]; ov = acc[3][0]; \
      cc = sigf(fv) * cst[0] + sigf(iv) * tanhf_(gv); cst[0] = cc; \
      hh = sigf(ov) * tanhf_(cc); th = tanhf_(hh); \
      hbuf[PB ^ 1][r0 + 0][so0] = f2bf(hh); thbuf[r0 + 0][so0] = f2bf(th); \
      iv = acc[0][1]; fv = acc[1][1]; gv = acc[2][1]; ov = acc[3][1]; \
      cc = sigf(fv) * cst[1] + sigf(iv) * tanhf_(gv); cst[1] = cc; \
      hh = sigf(ov) * tanhf_(cc); th = tanhf_(hh); \
      hbuf[PB ^ 1][r0 + 1][so1] = f2bf(hh); thbuf[r0 + 1][so1] = f2bf(th); \
      iv = acc[0][2]; fv = acc[1][2]; gv = acc[2][2]; ov = acc[3][2]; \
      cc = sigf(fv) * cst[2] + sigf(iv) * tanhf_(gv); cst[2] = cc; \
      hh = sigf(ov) * tanhf_(cc); th = tanhf_(hh); \
      hbuf[PB ^ 1][r0 + 2][so2] = f2bf(hh); thbuf[r0 + 2][so2] = f2bf(th); \
      iv = acc[0][3]; fv = acc[1][3]; gv = acc[2][3]; ov = acc[3][3]; \
      cc = sigf(fv) * cst[3] + sigf(iv) * tanhf_(gv); cst[3] = cc; \
      hh = sigf(ov) * tanhf_(cc); th = tanhf_(hh); \
      hbuf[PB ^ 1][r0 + 3][so3] = f2bf(hh); thbuf[r0 + 3][so3] = f2bf(th); \
    } \
    if (w >= 14 && s_ > 0) { \
      const int f = jn * 16 + c16, mi = (s_ - 1) & 15; \
      mubuf[mi][r0 + 0][f] = xacc[0]; \
      mubuf[mi][r0 + 1][f] = xacc[1]; \
      mubuf[mi][r0 + 2][f] = xacc[2]; \
      mubuf[mi][r0 + 3][f] = xacc[3]; \
    } \
    wg_barrier_lds(); /* B2: h_{s+1}/th_{s+1}/mu ready */ \
    if ((s_ & 15) == 0 && s_ > 0 && tid < 512) { \
      int b = tid >> 5, f = tid & 31; \
      float* dst = out + ((wg * 16 + b) << 13) + (f << 8) + (s_ - 16); \
      _Pragma("unroll") for (int j4 = 0; j4 < 4; ++j4) { \
        f32x4 vv; \
        _Pragma("unroll") for (int jj = 0; jj < 4; ++jj) vv[jj] = mubuf[j4 * 4 + jj][b][f]; \
        *reinterpret_cast<f32x4*>(dst + j4 * 4) = vv; \
      } \
    } \
  }

  for (int sp = 0; sp < 128; ++sp) {
    STEP(0, 2 * sp)
    STEP(1, 2 * sp + 1)
  }

  // ---- tail: x_256 -> mu col 255; flush cols 240-255; hst slot 255 ----
  if (w >= 14) {
    f32x4 xacc = {bo, bo, bo, bo};
    xacc = MFMA(*reinterpret_cast<const bf16x8*>(&thbuf[c16][eo0]), BC(woutb[(jn * 8 + 0) * 64 + l]), xacc, 0, 0, 0);
    xacc = MFMA(*reinterpret_cast<const bf16x8*>(&thbuf[c16][eo1]), BC(woutb[(jn * 8 + 1) * 64 + l]), xacc, 0, 0, 0);
    xacc = MFMA(*reinterpret_cast<const bf16x8*>(&thbuf[c16][eo2]), BC(woutb[(jn * 8 + 2) * 64 + l]), xacc, 0, 0, 0);
    xacc = MFMA(*reinterpret_cast<const bf16x8*>(&thbuf[c16][eo3]), BC(woutb[(jn * 8 + 3) * 64 + l]), xacc, 0, 0, 0);
    xacc = MFMA(*reinterpret_cast<const bf16x8*>(&thbuf[c16][eo4]), BC(woutb[(jn * 8 + 4) * 64 + l]), xacc, 0, 0, 0);
    xacc = MFMA(*reinterpret_cast<const bf16x8*>(&thbuf[c16][eo5]), BC(woutb[(jn * 8 + 5) * 64 + l]), xacc, 0, 0, 0);
    xacc = MFMA(*reinterpret_cast<const bf16x8*>(&thbuf[c16][eo6]), BC(woutb[(jn * 8 + 6) * 64 + l]), xacc, 0, 0, 0);
    xacc = MFMA(*reinterpret_cast<const bf16x8*>(&thbuf[c16][eo7]), BC(woutb[(jn * 8 + 7) * 64 + l]), xacc, 0, 0, 0);
    const int f = jn * 16 + c16;
    mubuf[15][r0 + 0][f] = xacc[0];
    mubuf[15][r0 + 1][f] = xacc[1];
    mubuf[15][r0 + 2][f] = xacc[2];
    mubuf[15][r0 + 3][f] = xacc[3];
  }
  __syncthreads();
  if (tid < 512) {
    int b = tid >> 5, f = tid & 31;
    float* dst = out + ((wg * 16 + b) << 13) + (f << 8) + 240;
#pragma unroll
    for (int j4 = 0; j4 < 4; ++j4) {
      f32x4 vv;
#pragma unroll
      for (int jj = 0; jj < 4; ++jj) vv[jj] = mubuf[j4 * 4 + jj][b][f];
      *reinterpret_cast<f32x4*>(dst + j4 * 4) = vv;
    }
  }
  if (w < 8) {
    int r = tid >> 5;
    int h0 = (tid & 31) * 8;
    uint4 d = *reinterpret_cast<const uint4*>(&hbuf[0][r][h0 ^ ((r & 7) << 3)]);
    *reinterpret_cast<uint4*>(hst + ((wg * 16 + r) << 16) + (255 << 8) + h0) = d;
  }
}

// sigma = softplus(hs_flat @ W_sig^T + b_sig)
__global__ __launch_bounds__(512) void sigma_gemm(
    const unsigned short* __restrict__ hst, const unsigned short* __restrict__ Wt,
    const float* __restrict__ b_sig, float* __restrict__ out) {
  __shared__ float sred[8][16][32];
  const int tid = threadIdx.x;
  const int w = tid >> 6;
  const int l = tid & 63;
  const int c16 = l & 15;
  const int g4 = l >> 4;
  const int wg = blockIdx.x;

  const unsigned short* ap =
      hst + (((wg << 2) + (c16 & 3)) << 16) + ((w * 32) << 8) + (g4 << 3);
  const unsigned short* bp0 = Wt + (c16 << 16) + ((w * 32) << 8) + (g4 << 3);
  const unsigned short* bp1 = Wt + ((16 + c16) << 16) + ((w * 32) << 8) + (g4 << 3);

  f32x4 a0 = {0.f, 0.f, 0.f, 0.f}, a1 = {0.f, 0.f, 0.f, 0.f};
#pragma unroll 8
  for (int kk = 0; kk < 256; ++kk) {
    int off = ((kk >> 3) << 8) + ((kk & 7) << 5);
    bf16x8 av = *reinterpret_cast<const bf16x8*>(ap + off);
    a0 = MFMA(av, *reinterpret_cast<const bf16x8*>(bp0 + off), a0, 0, 0, 0);
    a1 = MFMA(av, *reinterpret_cast<const bf16x8*>(bp1 + off), a1, 0, 0, 0);
  }
#pragma unroll
  for (int v = 0; v < 4; ++v) {
    sred[w][g4 * 4 + v][c16] = a0[v];
    sred[w][g4 * 4 + v][16 + c16] = a1[v];
  }
  __syncthreads();
  int b = tid >> 5, f = tid & 31;
  if (b < 4) {
    float acc = b_sig[f];
#pragma unroll
    for (int ww = 0; ww < 8; ++ww) acc += sred[ww][b][f];
    float sp = fmaxf(acc, 0.0f) + log1pf(__expf(-fabsf(acc)));
    out[BATCH * NF * SLEN + ((wg << 2) + b) * NF + f] = sp;
  }
}

extern "C" void kernel_launch(void* const* d_in, const int* in_sizes, int n_in,
                              void* d_out, int out_size, void* d_ws, size_t ws_size,
                              hipStream_t stream) {
  (void)in_sizes; (void)n_in; (void)out_size; (void)ws_size;
  const float* z     = (const float*)d_in[0];
  const float* W_lat = (const float*)d_in[1];
  const float* b_lat = (const float*)d_in[2];
  const float* W_ih  = (const float*)d_in[3];
  const float* b_ih  = (const float*)d_in[4];
  const float* W_hh  = (const float*)d_in[5];
  const float* b_hh  = (const float*)d_in[6];
  const float* W_out = (const float*)d_in[7];
  const float* b_out = (const float*)d_in[8];
  const float* W_sig = (const float*)d_in[9];
  const float* b_sig = (const float*)d_in[10];
  char* wsb = (char*)d_ws;
  uint4* ws = (uint4*)wsb;
  unsigned short* Wt  = (unsigned short*)(wsb + WT_BYTE);
  unsigned short* hst = (unsigned short*)(wsb + HST_BYTE);
  float* out = (float*)d_out;

  prep_weights<<<(PREP1_N + 255) / 256, 256, 0, stream>>>(W_hh, W_ih, W_out, W_lat, ws);
  prep_wt<<<256, 256, 0, stream>>>(W_sig, Wt);
  lstm_scan<<<64, 1024, 0, stream>>>(z, b_lat, b_ih, b_hh, b_out, ws, hst, out);
  sigma_gemm<<<256, 512, 0, stream>>>(hst, Wt, b_sig, out);
}

// Round 15
// 3141.105 us; speedup vs baseline: 1.4062x; 1.2191x over previous
//
#include <hip/hip_runtime.h>

#define NF 32
#define HDIM 256
#define SLEN 256
#define BATCH 1024

typedef float f32x4 __attribute__((ext_vector_type(4)));
typedef __bf16 bf16x8 __attribute__((ext_vector_type(8)));
typedef unsigned short u16;

#define MFMA __builtin_amdgcn_mfma_f32_16x16x32_bf16
#define BC(x) __builtin_bit_cast(bf16x8, x)

// ---- ws layout ----
#define WHH_O 0       // 64 j * 8 t * 64 l  = 32768 slots
#define WIH_O 32768   // 64 j * 64 l        =  4096
#define WOUT_O 36864  //  2 j * 8 t * 64 l  =  1024
#define WLAT_O 37888  // 32 j * 2 t * 64 l  =  4096
#define PREP1_N 41984
#define WT_BYTE (1u << 20)
#define HST_BYTE (8u << 20)

__device__ __forceinline__ u16 f2bf(float x) {
  __bf16 b = (__bf16)x;
  return __builtin_bit_cast(u16, b);
}
__device__ __forceinline__ unsigned int pk2(float a, float b) {
  return (unsigned int)f2bf(a) | ((unsigned int)f2bf(b) << 16);
}
__device__ __forceinline__ float sigf(float x) {
  return __fdividef(1.0f, 1.0f + __expf(-x));
}
__device__ __forceinline__ float tanhf_(float x) {
  return 1.0f - __fdividef(2.0f, __expf(2.0f * x) + 1.0f);
}
__device__ __forceinline__ void wg_barrier_lds() {
  asm volatile("s_waitcnt lgkmcnt(0)" ::: "memory");
  __builtin_amdgcn_s_barrier();
}

__global__ void prep_weights(const float* __restrict__ Whh, const float* __restrict__ Wih,
                             const float* __restrict__ Wout, const float* __restrict__ Wlat,
                             uint4* __restrict__ ws) {
  int i = blockIdx.x * 256 + threadIdx.x;
  if (i >= PREP1_N) return;
  int l = i & 63;
  int c16 = l & 15, g4 = l >> 4;
  const float* src;
  if (i < WIH_O) {
    int t = (i >> 6) & 7, j = i >> 9;
    src = Whh + (j * 16 + c16) * 256 + t * 32 + 8 * g4;
  } else if (i < WOUT_O) {
    int ii = i - WIH_O;
    int j = ii >> 6;
    src = Wih + (j * 16 + c16) * 32 + 8 * g4;
  } else if (i < WLAT_O) {
    int ii = i - WOUT_O;
    int t = (ii >> 6) & 7, j = ii >> 9;
    src = Wout + (j * 16 + c16) * 256 + t * 32 + 8 * g4;
  } else {
    int ii = i - WLAT_O;
    int t = (ii >> 6) & 1, j = ii >> 7;
    src = Wlat + (j * 16 + c16) * 64 + t * 32 + 8 * g4;
  }
  uint4 P;
  P.x = pk2(src[0], src[1]);
  P.y = pk2(src[2], src[3]);
  P.z = pk2(src[4], src[5]);
  P.w = pk2(src[6], src[7]);
  ws[i] = P;
}

__global__ void prep_wt(const float* __restrict__ Wsig, unsigned short* __restrict__ Wt) {
  __shared__ float tile[32][257];
  int f = blockIdx.x >> 3, hb = blockIdx.x & 7;
  int tid = threadIdx.x;
  const float* src = Wsig + f * (HDIM * SLEN) + hb * 32 * 256;
#pragma unroll
  for (int i = 0; i < 32; ++i) tile[i][tid] = src[i * 256 + tid];
  __syncthreads();
  int s = tid;
  unsigned short tmp[32];
#pragma unroll
  for (int h = 0; h < 32; ++h) tmp[h] = f2bf(tile[h][s]);
  uint4* dst = (uint4*)(Wt + f * 65536 + s * 256 + hb * 32);
  const uint4* tsrc = (const uint4*)tmp;
#pragma unroll
  for (int j = 0; j < 4; ++j) dst[j] = tsrc[j];
}

// Persistent LSTM scan: 64 WGs x 16 batch rows, 16 waves, 256 steps.
// r12 structure (x-GEMM in phase 3, so xacc is never live with gate accs)
// with named 2-bank W_hh prefetch CONFINED to the MFMA region: banks are
// loaded at step top and dead before the elementwise — no live range
// crosses a barrier, so no spill (r13/r14 lesson). Zero shift movs.
__global__ __launch_bounds__(1024, 4) void lstm_scan(
    const float* __restrict__ z, const float* __restrict__ b_lat,
    const float* __restrict__ b_ih, const float* __restrict__ b_hh,
    const float* __restrict__ b_out,
    const uint4* __restrict__ ws, unsigned short* __restrict__ hst,
    float* __restrict__ out) {
  __shared__ __align__(16) uint4 wihl[4096];              // 64KB
  __shared__ __align__(16) uint4 woutb[1024];             // 16KB
  __shared__ __align__(16) u16 hbuf[2][16][256];          // 16KB (swizzled)
  __shared__ __align__(16) u16 thbuf[16][256];            // 8KB  (swizzled; z-stage)
  __shared__ __align__(16) u16 xbuf[2][16][32];           // 2KB
  __shared__ __align__(16) float mubuf[16][16][32];       // 32KB

  const int tid = threadIdx.x, w = tid >> 6, l = tid & 63;
  const int c16 = l & 15, g4 = l >> 4, r0 = g4 * 4;
  const int wg = blockIdx.x;
  const int swz = (c16 & 7) << 3;

  for (int i = tid; i < 4096; i += 1024) wihl[i] = ws[WIH_O + i];
  if (tid < 1024) woutb[tid] = ws[WOUT_O + tid];

  // W_hh stream bases biased at kt=4: imm offsets (kt-4)*1024B in [-4096,3072]
  const uint4* bs0 = ws + WHH_O + ((0 * 16 + w) * 8 + 4) * 64 + l;
  const uint4* bs1 = ws + WHH_O + ((1 * 16 + w) * 8 + 4) * 64 + l;
  const uint4* bs2 = ws + WHH_O + ((2 * 16 + w) * 8 + 4) * 64 + l;
  const uint4* bs3 = ws + WHH_O + ((3 * 16 + w) * 8 + 4) * 64 + l;

  float biasv[4];
#pragma unroll
  for (int gi = 0; gi < 4; ++gi) {
    int n = (gi * 16 + w) * 16 + c16;
    biasv[gi] = b_ih[n] + b_hh[n];
  }
  const int jn = w - 14;
  const float bo = (w >= 14) ? b_out[jn * 16 + c16] : 0.f;
  const int hc = w * 16 + c16;

  // hoisted LDS element offsets
  const int eo0 = (0 * 32 + 8 * g4) ^ swz, eo1 = (1 * 32 + 8 * g4) ^ swz;
  const int eo2 = (2 * 32 + 8 * g4) ^ swz, eo3 = (3 * 32 + 8 * g4) ^ swz;
  const int eo4 = (4 * 32 + 8 * g4) ^ swz, eo5 = (5 * 32 + 8 * g4) ^ swz;
  const int eo6 = (6 * 32 + 8 * g4) ^ swz, eo7 = (7 * 32 + 8 * g4) ^ swz;
  const int so0 = hc ^ (((r0 + 0) & 7) << 3), so1 = hc ^ (((r0 + 1) & 7) << 3);
  const int so2 = hc ^ (((r0 + 2) & 7) << 3), so3 = hc ^ (((r0 + 3) & 7) << 3);

  // ---- init: z -> thbuf staging, x0 = 0 ----
  thbuf[tid >> 6][tid & 63] = f2bf(z[(wg * 16 + (tid >> 6)) * 64 + (tid & 63)]);
  if (tid < 512) xbuf[0][tid >> 5][tid & 31] = 0;
  __syncthreads();

  float cst[4];
  {
    bf16x8 za0 = *reinterpret_cast<const bf16x8*>(&thbuf[c16][8 * g4]);
    bf16x8 za1 = *reinterpret_cast<const bf16x8*>(&thbuf[c16][32 + 8 * g4]);
    float blh = b_lat[w * 16 + c16];
    float blc = b_lat[256 + w * 16 + c16];
    f32x4 ah = {blh, blh, blh, blh}, ac = {blc, blc, blc, blc};
    ah = MFMA(za0, *reinterpret_cast<const bf16x8*>(ws + WLAT_O + (w * 2 + 0) * 64 + l), ah, 0, 0, 0);
    ah = MFMA(za1, *reinterpret_cast<const bf16x8*>(ws + WLAT_O + (w * 2 + 1) * 64 + l), ah, 0, 0, 0);
    ac = MFMA(za0, *reinterpret_cast<const bf16x8*>(ws + WLAT_O + ((16 + w) * 2 + 0) * 64 + l), ac, 0, 0, 0);
    ac = MFMA(za1, *reinterpret_cast<const bf16x8*>(ws + WLAT_O + ((16 + w) * 2 + 1) * 64 + l), ac, 0, 0, 0);
    cst[0] = ac[0]; cst[1] = ac[1]; cst[2] = ac[2]; cst[3] = ac[3];
    hbuf[0][r0 + 0][so0] = f2bf(ah[0]);
    hbuf[0][r0 + 1][so1] = f2bf(ah[1]);
    hbuf[0][r0 + 2][so2] = f2bf(ah[2]);
    hbuf[0][r0 + 3][so3] = f2bf(ah[3]);
  }
  __syncthreads();

#define LOADPF(PF, OFF) \
  PF[0] = bs0[(OFF) * 64]; PF[1] = bs1[(OFF) * 64]; \
  PF[2] = bs2[(OFF) * 64]; PF[3] = bs3[(OFF) * 64];

// consume PF for this kt, refill PF with kt+2 (offset literal)
#define GKT(PB, EO, PF, LOFF) { \
    bf16x8 afr = *reinterpret_cast<const bf16x8*>(&hbuf[PB][c16][EO]); \
    acc[0] = MFMA(afr, BC(PF[0]), acc[0], 0, 0, 0); \
    acc[1] = MFMA(afr, BC(PF[1]), acc[1], 0, 0, 0); \
    acc[2] = MFMA(afr, BC(PF[2]), acc[2], 0, 0, 0); \
    acc[3] = MFMA(afr, BC(PF[3]), acc[3], 0, 0, 0); \
    LOADPF(PF, LOFF) }

// last consumers: no refill (banks die here, before elementwise)
#define GKTL(PB, EO, PF) { \
    bf16x8 afr = *reinterpret_cast<const bf16x8*>(&hbuf[PB][c16][EO]); \
    acc[0] = MFMA(afr, BC(PF[0]), acc[0], 0, 0, 0); \
    acc[1] = MFMA(afr, BC(PF[1]), acc[1], 0, 0, 0); \
    acc[2] = MFMA(afr, BC(PF[2]), acc[2], 0, 0, 0); \
    acc[3] = MFMA(afr, BC(PF[3]), acc[3], 0, 0, 0); }

#define STEP(PB, S_) { \
    const int s_ = (S_); \
    uint4 pfA[4], pfB[4]; \
    LOADPF(pfA, -4) LOADPF(pfB, -3) /* kt0, kt1 */ \
    f32x4 acc[4]; \
    acc[0] = (f32x4){biasv[0], biasv[0], biasv[0], biasv[0]}; \
    acc[1] = (f32x4){biasv[1], biasv[1], biasv[1], biasv[1]}; \
    acc[2] = (f32x4){biasv[2], biasv[2], biasv[2], biasv[2]}; \
    acc[3] = (f32x4){biasv[3], biasv[3], biasv[3], biasv[3]}; \
    __builtin_amdgcn_s_setprio(1); \
    GKT(PB, eo0, pfA, -2) GKT(PB, eo1, pfB, -1) /* kt0,kt1; refill kt2,kt3 */ \
    GKT(PB, eo2, pfA, 0)  GKT(PB, eo3, pfB, 1)  /* kt2,kt3; refill kt4,kt5 */ \
    GKT(PB, eo4, pfA, 2)  GKT(PB, eo5, pfB, 3)  /* kt4,kt5; refill kt6,kt7 */ \
    GKTL(PB, eo6, pfA)    GKTL(PB, eo7, pfB)    /* kt6,kt7; banks dead */ \
    __builtin_amdgcn_s_setprio(0); \
    { \
      bf16x8 xfr = *reinterpret_cast<const bf16x8*>(&xbuf[PB][c16][8 * g4]); \
      acc[0] = MFMA(xfr, BC(wihl[(0 * 16 + w) * 64 + l]), acc[0], 0, 0, 0); \
      acc[1] = MFMA(xfr, BC(wihl[(1 * 16 + w) * 64 + l]), acc[1], 0, 0, 0); \
      acc[2] = MFMA(xfr, BC(wihl[(2 * 16 + w) * 64 + l]), acc[2], 0, 0, 0); \
      acc[3] = MFMA(xfr, BC(wihl[(3 * 16 + w) * 64 + l]), acc[3], 0, 0, 0); \
    } \
    { \
      float iv, fv, gv, ov, cc, hh, th; \
      iv = acc[0][0]; fv = acc[1][0]; gv = acc[2][0]; ov = acc[3][0]; \
      cc = sigf(fv) * cst[0] + sigf(iv) * tanhf_(gv); cst[0] = cc; \
      hh = sigf(ov) * tanhf_(cc); th = tanhf_(hh); \
      hbuf[PB ^ 1][r0 + 0][so0] = f2bf(hh); thbuf[r0 + 0][so0] = f2bf(th); \
      iv = acc[0][1]; fv = acc[1][1]; gv = acc[2][1]; ov = acc[3][1]; \
      cc = sigf(fv) * cst[1] + sigf(iv) * tanhf_(gv); cst[1] = cc; \
      hh = sigf(ov) * tanhf_(cc); th = tanhf_(hh); \
      hbuf[PB ^ 1][r0 + 1][so1] = f2bf(hh); thbuf[r0 + 1][so1] = f2bf(th); \
      iv = acc[0][2]; fv = acc[1][2]; gv = acc[2][2]; ov = acc[3][2]; \
      cc = sigf(fv) * cst[2] + sigf(iv) * tanhf_(gv); cst[2] = cc; \
      hh = sigf(ov) * tanhf_(cc); th = tanhf_(hh); \
      hbuf[PB ^ 1][r0 + 2][so2] = f2bf(hh); thbuf[r0 + 2][so2] = f2bf(th); \
      iv = acc[0][3]; fv = acc[1][3]; gv = acc[2][3]; ov = acc[3][3]; \
      cc = sigf(fv) * cst[3] + sigf(iv) * tanhf_(gv); cst[3] = cc; \
      hh = sigf(ov) * tanhf_(cc); th = tanhf_(hh); \
      hbuf[PB ^ 1][r0 + 3][so3] = f2bf(hh); thbuf[r0 + 3][so3] = f2bf(th); \
    } \
    wg_barrier_lds(); /* B1: h_{s+1}/th_{s+1} visible */ \
    if (w >= 14) { \
      f32x4 xacc = {bo, bo, bo, bo}; \
      xacc = MFMA(*reinterpret_cast<const bf16x8*>(&thbuf[c16][eo0]), BC(woutb[(jn * 8 + 0) * 64 + l]), xacc, 0, 0, 0); \
      xacc = MFMA(*reinterpret_cast<const bf16x8*>(&thbuf[c16][eo1]), BC(woutb[(jn * 8 + 1) * 64 + l]), xacc, 0, 0, 0); \
      xacc = MFMA(*reinterpret_cast<const bf16x8*>(&thbuf[c16][eo2]), BC(woutb[(jn * 8 + 2) * 64 + l]), xacc, 0, 0, 0); \
      xacc = MFMA(*reinterpret_cast<const bf16x8*>(&thbuf[c16][eo3]), BC(woutb[(jn * 8 + 3) * 64 + l]), xacc, 0, 0, 0); \
      xacc = MFMA(*reinterpret_cast<const bf16x8*>(&thbuf[c16][eo4]), BC(woutb[(jn * 8 + 4) * 64 + l]), xacc, 0, 0, 0); \
      xacc = MFMA(*reinterpret_cast<const bf16x8*>(&thbuf[c16][eo5]), BC(woutb[(jn * 8 + 5) * 64 + l]), xacc, 0, 0, 0); \
      xacc = MFMA(*reinterpret_cast<const bf16x8*>(&thbuf[c16][eo6]), BC(woutb[(jn * 8 + 6) * 64 + l]), xacc, 0, 0, 0); \
      xacc = MFMA(*reinterpret_cast<const bf16x8*>(&thbuf[c16][eo7]), BC(woutb[(jn * 8 + 7) * 64 + l]), xacc, 0, 0, 0); \
      const int f = jn * 16 + c16; \
      const int sw = s_ & 15; \
      xbuf[PB ^ 1][r0 + 0][f] = f2bf(xacc[0]); mubuf[sw][r0 + 0][f] = xacc[0]; \
      xbuf[PB ^ 1][r0 + 1][f] = f2bf(xacc[1]); mubuf[sw][r0 + 1][f] = xacc[1]; \
      xbuf[PB ^ 1][r0 + 2][f] = f2bf(xacc[2]); mubuf[sw][r0 + 2][f] = xacc[2]; \
      xbuf[PB ^ 1][r0 + 3][f] = f2bf(xacc[3]); mubuf[sw][r0 + 3][f] = xacc[3]; \
    } else if (w < 8) { \
      int r = tid >> 5; \
      int h0 = (tid & 31) * 8; \
      uint4 d = *reinterpret_cast<const uint4*>(&hbuf[PB ^ 1][r][h0 ^ ((r & 7) << 3)]); \
      *reinterpret_cast<uint4*>(hst + ((wg * 16 + r) << 16) + (s_ << 8) + h0) = d; \
    } \
    wg_barrier_lds(); /* B2: xbuf/mubuf ready */ \
    if ((s_ & 15) == 15 && tid < 512) { \
      int b = tid >> 5, f = tid & 31; \
      float* dst = out + ((wg * 16 + b) << 13) + (f << 8) + (s_ - 15); \
      _Pragma("unroll") for (int j4 = 0; j4 < 4; ++j4) { \
        f32x4 vv; \
        _Pragma("unroll") for (int jj = 0; jj < 4; ++jj) vv[jj] = mubuf[j4 * 4 + jj][b][f]; \
        *reinterpret_cast<f32x4*>(dst + j4 * 4) = vv; \
      } \
    } \
  }

  for (int sp = 0; sp < 128; ++sp) {
    STEP(0, 2 * sp)
    STEP(1, 2 * sp + 1)
  }
}

// sigma = softplus(hs_flat @ W_sig^T + b_sig)
__global__ __launch_bounds__(512) void sigma_gemm(
    const unsigned short* __restrict__ hst, const unsigned short* __restrict__ Wt,
    const float* __restrict__ b_sig, float* __restrict__ out) {
  __shared__ float sred[8][16][32];
  const int tid = threadIdx.x;
  const int w = tid >> 6;
  const int l = tid & 63;
  const int c16 = l & 15;
  const int g4 = l >> 4;
  const int wg = blockIdx.x;

  const unsigned short* ap =
      hst + (((wg << 2) + (c16 & 3)) << 16) + ((w * 32) << 8) + (g4 << 3);
  const unsigned short* bp0 = Wt + (c16 << 16) + ((w * 32) << 8) + (g4 << 3);
  const unsigned short* bp1 = Wt + ((16 + c16) << 16) + ((w * 32) << 8) + (g4 << 3);

  f32x4 a0 = {0.f, 0.f, 0.f, 0.f}, a1 = {0.f, 0.f, 0.f, 0.f};
#pragma unroll 8
  for (int kk = 0; kk < 256; ++kk) {
    int off = ((kk >> 3) << 8) + ((kk & 7) << 5);
    bf16x8 av = *reinterpret_cast<const bf16x8*>(ap + off);
    a0 = MFMA(av, *reinterpret_cast<const bf16x8*>(bp0 + off), a0, 0, 0, 0);
    a1 = MFMA(av, *reinterpret_cast<const bf16x8*>(bp1 + off), a1, 0, 0, 0);
  }
#pragma unroll
  for (int v = 0; v < 4; ++v) {
    sred[w][g4 * 4 + v][c16] = a0[v];
    sred[w][g4 * 4 + v][16 + c16] = a1[v];
  }
  __syncthreads();
  int b = tid >> 5, f = tid & 31;
  if (b < 4) {
    float acc = b_sig[f];
#pragma unroll
    for (int ww = 0; ww < 8; ++ww) acc += sred[ww][b][f];
    float sp = fmaxf(acc, 0.0f) + log1pf(__expf(-fabsf(acc)));
    out[BATCH * NF * SLEN + ((wg << 2) + b) * NF + f] = sp;
  }
}

extern "C" void kernel_launch(void* const* d_in, const int* in_sizes, int n_in,
                              void* d_out, int out_size, void* d_ws, size_t ws_size,
                              hipStream_t stream) {
  (void)in_sizes; (void)n_in; (void)out_size; (void)ws_size;
  const float* z     = (const float*)d_in[0];
  const float* W_lat = (const float*)d_in[1];
  const float* b_lat = (const float*)d_in[2];
  const float* W_ih  = (const float*)d_in[3];
  const float* b_ih  = (const float*)d_in[4];
  const float* W_hh  = (const float*)d_in[5];
  const float* b_hh  = (const float*)d_in[6];
  const float* W_out = (const float*)d_in[7];
  const float* b_out = (const float*)d_in[8];
  const float* W_sig = (const float*)d_in[9];
  const float* b_sig = (const float*)d_in[10];
  char* wsb = (char*)d_ws;
  uint4* ws = (uint4*)wsb;
  unsigned short* Wt  = (unsigned short*)(wsb + WT_BYTE);
  unsigned short* hst = (unsigned short*)(wsb + HST_BYTE);
  float* out = (float*)d_out;

  prep_weights<<<(PREP1_N + 255) / 256, 256, 0, stream>>>(W_hh, W_ih, W_out, W_lat, ws);
  prep_wt<<<256, 256, 0, stream>>>(W_sig, Wt);
  lstm_scan<<<64, 1024, 0, stream>>>(z, b_lat, b_ih, b_hh, b_out, ws, hst, out);
  sigma_gemm<<<256, 512, 0, stream>>>(hst, Wt, b_sig, out);
}